// Round 1
// baseline (103.527 us; speedup 1.0000x reference)
//
#include <hip/hip_runtime.h>
#include <math.h>

namespace {
constexpr int H  = 8;
constexpr int D  = 64;
constexpr int NB = 32;   // number of 64-blocks along T
constexpr int BS = 64;   // block size
constexpr int QST = 68;  // padded LDS stride (critical path)
constexpr int KSPLIT = 8;          // ki-parallelism per (h,qi) row
constexpr int KCH = NB / KSPLIT;   // 4 k-blocks per chunk
}
#define FEPS 1e-6f

typedef unsigned short u16;
typedef unsigned int   u32;
typedef __attribute__((ext_vector_type(8))) short bf16x8;
typedef __attribute__((ext_vector_type(4))) float floatx4;

__device__ __forceinline__ u32 f2bf(float x) {
  union { float f; u32 u; } v; v.f = x;
  return (v.u + 0x7FFFu + ((v.u >> 16) & 1u)) >> 16;
}
__device__ __forceinline__ u32 pk2(float a, float b) { return f2bf(a) | (f2bf(b) << 16); }
#define ELU1(x) ((x) > 0.f ? (x) + 1.f : expf(x))
// XOR swizzle at 8-ushort granularity: row-major [64][64] bf16 tile
#define SWZ(row, kblk) ((row)*64 + (((kblk) ^ ((row)&7))*8))

// ---------------- Kernel P: fused prologue ----------------
// blocks 0..255  : kvT[c][d] = bf16((elu(k)+1)^T v), k_sum (f32), krep (f64 mean of k)
// blocks 256..511: qrep (f64 block mean of q)
__global__ __launch_bounds__(256) void prep_kernel(const float* __restrict__ q,
                                                   const float* __restrict__ k,
                                                   const float* __restrict__ v,
                                                   u16* __restrict__ kvt16,
                                                   float* __restrict__ ksum,
                                                   double* __restrict__ qrep,
                                                   double* __restrict__ krep) {
  __shared__ float smem[3*BS*D];          // 48 KB
  int bid = blockIdx.x;
  int tid = threadIdx.x;
  if (bid >= 256) {
    // ---- q block means ----
    double* qred = (double*)smem;
    int r = bid - 256;                    // h*NB + bi
    int h = r >> 5, bi = r & 31;
    int d = tid & 63, quarter = tid >> 6;
    double s = 0.0;
    for (int t = quarter*16; t < quarter*16 + 16; ++t)
      s += (double)q[((bi*BS + t)*H + h)*D + d];
    qred[quarter*64 + d] = s;
    __syncthreads();
    if (tid < 64)
      qrep[r*D + tid] = (qred[tid] + qred[64+tid] + qred[128+tid] + qred[192+tid]) * (1.0/64.0);
    return;
  }
  // ---- kv path ----
  float* kf   = smem;                     // [s][d] elu(k)+1
  float* vv   = smem + BS*D;              // [s][c]
  float* kraw = smem + 2*BS*D;            // [s][d] raw k
  int h = bid >> 5, ki = bid & 31;
  int sr = tid >> 2, cgp = tid & 3;
  const float4* kb = (const float4*)(k + ((ki*BS + sr)*H + h)*D);
  const float4* vb = (const float4*)(v + ((ki*BS + sr)*H + h)*D);
#pragma unroll
  for (int m = 0; m < 4; ++m) {
    float4 kk = kb[cgp*4 + m];
    float4 vx = vb[cgp*4 + m];
    int c = cgp*16 + m*4;
    *(float4*)&kraw[sr*D + c] = kk;
    kf[sr*D + c + 0] = ELU1(kk.x);
    kf[sr*D + c + 1] = ELU1(kk.y);
    kf[sr*D + c + 2] = ELU1(kk.z);
    kf[sr*D + c + 3] = ELU1(kk.w);
    *(float4*)&vv[sr*D + c] = vx;
  }
  __syncthreads();
  // thread owns (c = tid&63, d0 = (tid>>6)*16): kvT[c][d0..d0+15]
  int c = tid & 63, dg = tid >> 6, d0 = dg*16;
  float acc[16];
#pragma unroll
  for (int j = 0; j < 16; ++j) acc[j] = 0.f;
#pragma unroll 4
  for (int s2 = 0; s2 < BS; ++s2) {
    float vval = vv[s2*D + c];
    const float4* kr = (const float4*)&kf[s2*D + d0];
    float4 a0 = kr[0], a1 = kr[1], a2 = kr[2], a3 = kr[3];
    acc[0]  += vval*a0.x; acc[1]  += vval*a0.y; acc[2]  += vval*a0.z; acc[3]  += vval*a0.w;
    acc[4]  += vval*a1.x; acc[5]  += vval*a1.y; acc[6]  += vval*a1.z; acc[7]  += vval*a1.w;
    acc[8]  += vval*a2.x; acc[9]  += vval*a2.y; acc[10] += vval*a2.z; acc[11] += vval*a2.w;
    acc[12] += vval*a3.x; acc[13] += vval*a3.y; acc[14] += vval*a3.z; acc[15] += vval*a3.w;
  }
  // write bf16 (same rounding main applies — numerically identical downstream)
  u16* op = kvt16 + (size_t)bid*4096 + c*64 + d0;
  uint4 P0, P1;
  P0.x = pk2(acc[0],acc[1]);   P0.y = pk2(acc[2],acc[3]);
  P0.z = pk2(acc[4],acc[5]);   P0.w = pk2(acc[6],acc[7]);
  P1.x = pk2(acc[8],acc[9]);   P1.y = pk2(acc[10],acc[11]);
  P1.z = pk2(acc[12],acc[13]); P1.w = pk2(acc[14],acc[15]);
  *(uint4*)(op + 0) = P0;
  *(uint4*)(op + 8) = P1;
  if (dg == 0) {
    float ks = 0.f;
    for (int s2 = 0; s2 < BS; ++s2) ks += kf[s2*D + c];
    ksum[bid*D + c] = ks;
    double m = 0.0;
    for (int s2 = 0; s2 < BS; ++s2) m += (double)kraw[s2*D + c];
    krep[bid*D + c] = m * (1.0/64.0);
  }
}

// ---------------- Kernel B: bscores + per-row stats (32 blocks) ----------------
__global__ __launch_bounds__(256) void bscore_stats_kernel(const double* __restrict__ qrep,
                                                           const double* __restrict__ krep,
                                                           double* __restrict__ rowmin,
                                                           double* __restrict__ rowmax,
                                                           double* __restrict__ rowvar) {
  __shared__ double qs[8*64];     // 4 KB
  __shared__ double ks[32*65];    // 16.6 KB, padded stride 65
  int b = blockIdx.x;
  int h = b >> 2;
  int r0 = b*8;
  int tid = threadIdx.x;
  for (int i = tid; i < 512; i += 256) qs[i] = qrep[(size_t)r0*64 + i];
  for (int i = tid; i < 2048; i += 256) ks[(i >> 6)*65 + (i & 63)] = krep[(size_t)h*2048 + i];
  __syncthreads();
  int lr = tid >> 5, ki = tid & 31;
  double s = 0.0;
  const double* qr = qs + lr*64;
  const double* kr = ks + ki*65;
#pragma unroll 16
  for (int d = 0; d < D; ++d) s += qr[d]*kr[d];
  double bs = s * 0.125;                 // / sqrt(64)
  double rmax = bs, rmin = bs;
#pragma unroll
  for (int m = 1; m < 32; m <<= 1) {
    rmax = fmax(rmax, __shfl_xor(rmax, m, 64));
    rmin = fmin(rmin, __shfl_xor(rmin, m, 64));
  }
  double e = exp(bs - rmax);
  double S = e, S2 = e*e;
#pragma unroll
  for (int m = 1; m < 32; m <<= 1) {
    S  += __shfl_xor(S,  m, 64);
    S2 += __shfl_xor(S2, m, 64);
  }
  if (ki == 0) {
    double invS = 1.0 / S;
    double sp = S * invS;
    double mu = sp * (1.0/32.0);
    double var = (S2*invS*invS - 2.0*mu*sp + 32.0*mu*mu) * (1.0/31.0);
    rowmin[r0 + lr] = rmin;
    rowmax[r0 + lr] = rmax;
    rowvar[r0 + lr] = var;
  }
}

// ---------------- Kernel F: per-row flags (1 block) ----------------
__global__ __launch_bounds__(256) void flags_kernel(const double* __restrict__ rowmin,
                                                    const double* __restrict__ rowmax,
                                                    const double* __restrict__ rowvar,
                                                    int* __restrict__ flags) {
  __shared__ double redA[4];
  __shared__ double redB[4];
  int tid = threadIdx.x;
  int lane = tid & 63, wid = tid >> 6;
  double x = rowmin[tid];
#pragma unroll
  for (int m = 1; m < 64; m <<= 1) x = fmin(x, __shfl_xor(x, m, 64));
  if (lane == 0) redA[wid] = x;
  __syncthreads();
  double gmin = fmin(fmin(redA[0], redA[1]), fmin(redA[2], redA[3]));
  double rng = rowmax[tid] - gmin;
  if (rng < 1e-6) rng = 1e-6;             // jnp.maximum(max - min, EPS)
  double imp = rowvar[tid] * rng;
  __syncthreads();
  double a = imp, b2 = imp;
#pragma unroll
  for (int m = 1; m < 64; m <<= 1) {
    a  = fmin(a,  __shfl_xor(a,  m, 64));
    b2 = fmax(b2, __shfl_xor(b2, m, 64));
  }
  if (lane == 0) { redA[wid] = a; redB[wid] = b2; }
  __syncthreads();
  double imin = fmin(fmin(redA[0], redA[1]), fmin(redA[2], redA[3]));
  double imax = fmax(fmax(redB[0], redB[1]), fmax(redB[2], redB[3]));
  double impn = (imp - imin) / (imax - imin + 1e-6);
  flags[tid] = (impn >= 0.5) ? 2 : ((impn <= 0.01) ? 0 : 1);
}

// ---------------- Kernel D: main — ki-split partial attention ----------------
// grid = 256 rows * KSPLIT chunks; block bid = rowid*KSPLIT + split handles
// k-blocks [split*KCH, split*KCH+KCH). Both paths are additive over ki
// (per-(row,ki) softmax; linear path numerator/denominator additive), so each
// chunk writes f32 partial acc[64][64] + partial row-weight w[64]; combine sums.
__global__ __launch_bounds__(256) void main_kernel(
    const float* __restrict__ q, const float* __restrict__ k, const float* __restrict__ v,
    const u16* __restrict__ kvt16, const float* __restrict__ ksum,
    const int* __restrict__ flags, float* __restrict__ pacc, float* __restrict__ pw) {
  __shared__ __align__(16) float smem[13056];   // 52224 B (3 x [64][68] f32)
  int bid = blockIdx.x;
  int rowid = bid >> 3;                   // h*NB + qi
  int split = bid & (KSPLIT - 1);
  int h = rowid >> 5, qi = rowid & 31;
  int k0 = split * KCH;
  int tid = threadIdx.x;
  int row = tid >> 2, cgp = tid & 3, c0 = cgp*16;
  int lane = tid & 63;

  float* paccp = pacc + (size_t)bid * 4096;
  float* pwp   = pw   + (size_t)bid * 64;

  int flag = flags[rowid];
  if (flag == 0) {
    // negligible: w=0 signals combine to emit zeros without reading pacc
    if (tid < 64) pwp[tid] = 0.f;
    return;
  }

  if (flag == 1) {
    // ---- marginal: linear (ELU+1) attention via bf16 MFMA, double-buffered ----
    u16*  qfb  = (u16*)smem;              // [64][64] bf16, swizzled          (8 KB)
    u16*  kvb  = (u16*)(smem + 2048);     // 2 x [64][64] bf16, swizzled      (16 KB)
    float* idens = smem + 6144;           // [64][KCH] 1/den
    float* wsl   = smem + 6400;           // [64] sum of den over chunk
    float* kslc  = smem + 6464;           // [KCH][64] k_sum slice

    {
      const float4* kss = (const float4*)(ksum + (size_t)(h*NB + k0)*D);
      for (int i = tid; i < KCH*16; i += 256) ((float4*)kslc)[i] = kss[i];
    }
    float qf[16];
    {
      const float4* qp = (const float4*)(q + ((qi*BS + row)*H + h)*D + c0);
      float4 q0 = qp[0], q1 = qp[1], q2 = qp[2], q3 = qp[3];
      qf[0]=ELU1(q0.x); qf[1]=ELU1(q0.y); qf[2]=ELU1(q0.z); qf[3]=ELU1(q0.w);
      qf[4]=ELU1(q1.x); qf[5]=ELU1(q1.y); qf[6]=ELU1(q1.z); qf[7]=ELU1(q1.w);
      qf[8]=ELU1(q2.x); qf[9]=ELU1(q2.y); qf[10]=ELU1(q2.z); qf[11]=ELU1(q2.w);
      qf[12]=ELU1(q3.x); qf[13]=ELU1(q3.y); qf[14]=ELU1(q3.z); qf[15]=ELU1(q3.w);
      uint4 p0, p1;
      p0.x = pk2(qf[0],qf[1]);  p0.y = pk2(qf[2],qf[3]);
      p0.z = pk2(qf[4],qf[5]);  p0.w = pk2(qf[6],qf[7]);
      p1.x = pk2(qf[8],qf[9]);  p1.y = pk2(qf[10],qf[11]);
      p1.z = pk2(qf[12],qf[13]); p1.w = pk2(qf[14],qf[15]);
      *(uint4*)&qfb[SWZ(row, cgp*2)]     = p0;
      *(uint4*)&qfb[SWZ(row, cgp*2 + 1)] = p1;
    }
    const u16* kvbase = kvt16 + (size_t)(h*NB + k0)*4096 + (size_t)row*64 + c0;
    uint4 u0 = *(const uint4*)(kvbase + 0);
    uint4 u1 = *(const uint4*)(kvbase + 8);
    __syncthreads();
    // den[row][kk] exact f32: partial over 16 cols + shfl reduce over 4 lanes
    {
      float wloc = 0.f;
      for (int kk = 0; kk < KCH; ++kk) {
        float pd = 0.f;
#pragma unroll
        for (int j = 0; j < 16; ++j) pd += qf[j] * kslc[kk*64 + c0 + j];
        pd += __shfl_xor(pd, 1, 64);
        pd += __shfl_xor(pd, 2, 64);
        float den = pd + FEPS;
        if (cgp == 0) idens[row*KCH + kk] = 1.0f / den;
        wloc += den;
      }
      if (cgp == 0) wsl[row] = wloc;
    }
    *(uint4*)&kvb[SWZ(row, cgp*2)]     = u0;
    *(uint4*)&kvb[SWZ(row, cgp*2 + 1)] = u1;

    int w = tid >> 6, m = lane & 15, quad = lane >> 4;
    bf16x8 aLo = *(const bf16x8*)&qfb[SWZ(w*16 + m, quad)];
    bf16x8 aHi = *(const bf16x8*)&qfb[SWZ(w*16 + m, 4 + quad)];
    int rbase = w*16 + quad*4;
    float acc[16];
#pragma unroll
    for (int j = 0; j < 16; ++j) acc[j] = 0.f;

    for (int kk = 0; kk < KCH; ++kk) {
      if (kk + 1 < KCH) {
        const u16* kvp = kvbase + (size_t)(kk+1)*4096;
        u0 = *(const uint4*)(kvp + 0);
        u1 = *(const uint4*)(kvp + 8);
      }
      __syncthreads();                    // tile kk visible; reads of kk-1 done
      const u16* kb = kvb + (kk & 1)*4096;
      float i0 = idens[(rbase + 0)*KCH + kk];
      float i1 = idens[(rbase + 1)*KCH + kk];
      float i2 = idens[(rbase + 2)*KCH + kk];
      float i3 = idens[(rbase + 3)*KCH + kk];
      floatx4 zz = {0.f, 0.f, 0.f, 0.f};
#pragma unroll
      for (int t = 0; t < 4; ++t) {
        bf16x8 bLo = *(const bf16x8*)&kb[SWZ(t*16 + m, quad)];
        bf16x8 bHi = *(const bf16x8*)&kb[SWZ(t*16 + m, 4 + quad)];
        floatx4 c4 = __builtin_amdgcn_mfma_f32_16x16x32_bf16(aLo, bLo, zz, 0, 0, 0);
        c4 = __builtin_amdgcn_mfma_f32_16x16x32_bf16(aHi, bHi, c4, 0, 0, 0);
        acc[t*4+0] += c4[0]*i0;
        acc[t*4+1] += c4[1]*i1;
        acc[t*4+2] += c4[2]*i2;
        acc[t*4+3] += c4[3]*i3;
      }
      if (kk + 1 < KCH) {
        u16* kw = kvb + ((kk+1) & 1)*4096;
        *(uint4*)&kw[SWZ(row, cgp*2)]     = u0;
        *(uint4*)&kw[SWZ(row, cgp*2 + 1)] = u1;
      }
    }
#pragma unroll
    for (int r = 0; r < 4; ++r)
#pragma unroll
      for (int t = 0; t < 4; ++t)
        paccp[(rbase + r)*64 + t*16 + m] = acc[t*4 + r];
    if (tid < 64) pwp[tid] = wsl[tid];
    return;
  }

  // ---- critical: f32 per-(row,ki) softmax attention over chunk's KCH k-blocks ----
  float* bufA = smem;                 // q*scale, [row][d] stride QST
  float* bufK = smem + 4352;          // K transposed: [d][s] stride QST (b128 broadcast reads)
  float* bufV = smem + 8704;          // V: [s][d] stride QST
  {
    const float4* qp = (const float4*)(q + ((qi*BS + row)*H + h)*D);
#pragma unroll
    for (int mm = 0; mm < 4; ++mm) {
      float4 qq = qp[cgp*4 + mm];
      int c = c0 + mm*4;
      bufA[row*QST + c + 0] = qq.x*0.125f;
      bufA[row*QST + c + 1] = qq.y*0.125f;
      bufA[row*QST + c + 2] = qq.z*0.125f;
      bufA[row*QST + c + 3] = qq.w*0.125f;
    }
  }
  // prefetch chunk's first K/V tile into registers (T14 async-stage split)
  float4 kreg[4], vreg[4];
  {
    const float4* kp = (const float4*)(k + ((k0*BS + row)*H + h)*D);
    const float4* vp = (const float4*)(v + ((k0*BS + row)*H + h)*D);
#pragma unroll
    for (int mm = 0; mm < 4; ++mm) { kreg[mm] = kp[cgp*4 + mm]; vreg[mm] = vp[cgp*4 + mm]; }
  }
  float acc[16];
#pragma unroll
  for (int j = 0; j < 16; ++j) acc[j] = 0.f;
  float wsum = 0.f;

#pragma unroll 1
  for (int kk = 0; kk < KCH; ++kk) {
    // write staged K (transposed) and V to LDS
#pragma unroll
    for (int mm = 0; mm < 4; ++mm) {
      int c = c0 + mm*4;
      bufK[(c+0)*QST + row] = kreg[mm].x;
      bufK[(c+1)*QST + row] = kreg[mm].y;
      bufK[(c+2)*QST + row] = kreg[mm].z;
      bufK[(c+3)*QST + row] = kreg[mm].w;
      *(float4*)&bufV[row*QST + c] = vreg[mm];
    }
    __syncthreads();
    if (kk + 1 < KCH) {
      int ki1 = k0 + kk + 1;
      const float4* kp = (const float4*)(k + ((ki1*BS + row)*H + h)*D);
      const float4* vp = (const float4*)(v + ((ki1*BS + row)*H + h)*D);
#pragma unroll
      for (int mm = 0; mm < 4; ++mm) { kreg[mm] = kp[cgp*4 + mm]; vreg[mm] = vp[cgp*4 + mm]; }
    }
    // scores: sc[j] = sum_d qs[row][d] * k[c0+j][d]  (b128 broadcast reads)
    float sc[16];
#pragma unroll
    for (int j = 0; j < 16; ++j) sc[j] = 0.f;
#pragma unroll 4
    for (int d4 = 0; d4 < 16; ++d4) {
      float4 a4 = *(const float4*)&bufA[row*QST + d4*4];
      float av[4] = {a4.x, a4.y, a4.z, a4.w};
#pragma unroll
      for (int x = 0; x < 4; ++x) {
        const float4* br = (const float4*)&bufK[(d4*4 + x)*QST + c0];
        float4 b0 = br[0], b1 = br[1], b2 = br[2], b3 = br[3];
        float a = av[x];
        sc[0]  += a*b0.x; sc[1]  += a*b0.y; sc[2]  += a*b0.z; sc[3]  += a*b0.w;
        sc[4]  += a*b1.x; sc[5]  += a*b1.y; sc[6]  += a*b1.z; sc[7]  += a*b1.w;
        sc[8]  += a*b2.x; sc[9]  += a*b2.y; sc[10] += a*b2.z; sc[11] += a*b2.w;
        sc[12] += a*b3.x; sc[13] += a*b3.y; sc[14] += a*b3.z; sc[15] += a*b3.w;
      }
    }
    float mx = sc[0];
#pragma unroll
    for (int j = 1; j < 16; ++j) mx = fmaxf(mx, sc[j]);
    mx = fmaxf(mx, __shfl_xor(mx, 1, 64));
    mx = fmaxf(mx, __shfl_xor(mx, 2, 64));
    float es = 0.f;
    float p[16];
#pragma unroll
    for (int j = 0; j < 16; ++j) { p[j] = expf(sc[j] - mx); es += p[j]; }
    es += __shfl_xor(es, 1, 64);
    es += __shfl_xor(es, 2, 64);
    float inv = 1.0f / es;
#pragma unroll
    for (int j = 0; j < 16; ++j) p[j] *= inv;
    wsum += es * inv;
    // PV: static p-index (registers, not scratch)
#pragma unroll 1
    for (int g = 0; g < 4; ++g) {
      int src = (lane & ~3) | g;
#pragma unroll
      for (int jj = 0; jj < 16; ++jj) {
        float pv = __shfl(p[jj], src, 64);
        const float4* vr = (const float4*)&bufV[(g*16 + jj)*QST + c0];
        float4 a0 = vr[0], a1 = vr[1], a2 = vr[2], a3 = vr[3];
        acc[0]  += pv*a0.x; acc[1]  += pv*a0.y; acc[2]  += pv*a0.z; acc[3]  += pv*a0.w;
        acc[4]  += pv*a1.x; acc[5]  += pv*a1.y; acc[6]  += pv*a1.z; acc[7]  += pv*a1.w;
        acc[8]  += pv*a2.x; acc[9]  += pv*a2.y; acc[10] += pv*a2.z; acc[11] += pv*a2.w;
        acc[12] += pv*a3.x; acc[13] += pv*a3.y; acc[14] += pv*a3.z; acc[15] += pv*a3.w;
      }
    }
    __syncthreads();   // compute done before next iteration's LDS writes
  }
  // write f32 partials (combine divides by summed w)
  float* pp = paccp + row*64 + c0;
  *(float4*)(pp + 0)  = make_float4(acc[0],  acc[1],  acc[2],  acc[3]);
  *(float4*)(pp + 4)  = make_float4(acc[4],  acc[5],  acc[6],  acc[7]);
  *(float4*)(pp + 8)  = make_float4(acc[8],  acc[9],  acc[10], acc[11]);
  *(float4*)(pp + 12) = make_float4(acc[12], acc[13], acc[14], acc[15]);
  if (cgp == 0) pwp[row] = wsum;
}

// ---------------- Kernel C: combine partials ----------------
__global__ __launch_bounds__(256) void combine_kernel(const float* __restrict__ pacc,
                                                      const float* __restrict__ pw,
                                                      float* __restrict__ out) {
  int rowid = blockIdx.x;                 // h*NB + qi
  int h = rowid >> 5, qi = rowid & 31;
  int tid = threadIdx.x;
  int row = tid >> 2, c0 = (tid & 3)*16;
  float w = 0.f;
  const float* pwb = pw + (size_t)rowid * KSPLIT * 64 + row;
#pragma unroll
  for (int s = 0; s < KSPLIT; ++s) w += pwb[s*64];
  float* op = out + ((qi*BS + row)*H + h)*D + c0;
  if (w == 0.f) {
    // negligible row: 0/(0+eps) = 0 exactly; skip reading pacc entirely
    float4 z = make_float4(0.f, 0.f, 0.f, 0.f);
    ((float4*)op)[0] = z; ((float4*)op)[1] = z; ((float4*)op)[2] = z; ((float4*)op)[3] = z;
    return;
  }
  floatx4 s0 = {0,0,0,0}, s1 = {0,0,0,0}, s2 = {0,0,0,0}, s3 = {0,0,0,0};
  const float* base = pacc + (size_t)rowid * KSPLIT * 4096 + row*64 + c0;
#pragma unroll
  for (int s = 0; s < KSPLIT; ++s) {
    const floatx4* p4 = (const floatx4*)(base + (size_t)s*4096);
    s0 += p4[0]; s1 += p4[1]; s2 += p4[2]; s3 += p4[3];
  }
  float wd = 1.0f / (w + FEPS);
  ((float4*)op)[0] = make_float4(s0[0]*wd, s0[1]*wd, s0[2]*wd, s0[3]*wd);
  ((float4*)op)[1] = make_float4(s1[0]*wd, s1[1]*wd, s1[2]*wd, s1[3]*wd);
  ((float4*)op)[2] = make_float4(s2[0]*wd, s2[1]*wd, s2[2]*wd, s2[3]*wd);
  ((float4*)op)[3] = make_float4(s3[0]*wd, s3[1]*wd, s3[2]*wd, s3[3]*wd);
}

extern "C" void kernel_launch(void* const* d_in, const int* in_sizes, int n_in,
                              void* d_out, int out_size, void* d_ws, size_t ws_size,
                              hipStream_t stream) {
  const float* q = (const float*)d_in[0];
  const float* k = (const float*)d_in[1];
  const float* v = (const float*)d_in[2];
  float* out = (float*)d_out;
  char* ws = (char*)d_ws;
  // workspace layout (16B-aligned)
  u16*    kvw  = (u16*)   (ws + 0);                    // 256*4096 u16 (2 MB)
  float*  ksw  = (float*) (ws + 2097152);              // 16384 floats
  double* krep = (double*)(ws + 2162688);              // 16384 doubles
  double* qrep = (double*)(ws + 2293760);              // 16384 doubles
  double* rmn  = (double*)(ws + 2424832);              // 256 doubles
  double* rmx  = (double*)(ws + 2426880);              // 256 doubles
  double* rvr  = (double*)(ws + 2428928);              // 256 doubles
  int*    flg  = (int*)   (ws + 2430976);              // 256 ints
  float*  pacc = (float*) (ws + 4194304);              // 2048*4096 f32 (32 MB)
  float*  pw   = (float*) (ws + 4194304 + 33554432);   // 2048*64 f32 (512 KB)

  prep_kernel<<<512, 256, 0, stream>>>(q, k, v, kvw, ksw, qrep, krep);
  bscore_stats_kernel<<<32, 256, 0, stream>>>(qrep, krep, rmn, rmx, rvr);
  flags_kernel<<<1, 256, 0, stream>>>(rmn, rmx, rvr, flg);
  main_kernel<<<256*KSPLIT, 256, 0, stream>>>(q, k, v, kvw, ksw, flg, pacc, pw);
  combine_kernel<<<256, 256, 0, stream>>>(pacc, pw, out);
}

// Round 2
// 99.408 us; speedup vs baseline: 1.0414x; 1.0414x over previous
//
#include <hip/hip_runtime.h>
#include <math.h>

namespace {
constexpr int H  = 8;
constexpr int D  = 64;
constexpr int NB = 32;   // number of 64-blocks along T
constexpr int BS = 64;   // block size
constexpr int KSPLIT = 4;          // ki-parallelism per (h,qi) row
constexpr int KCH = NB / KSPLIT;   // 8 k-blocks per chunk
}
#define FEPS 1e-6f

typedef unsigned short u16;
typedef unsigned int   u32;
typedef __attribute__((ext_vector_type(8))) short bf16x8;
typedef __attribute__((ext_vector_type(4))) float floatx4;

__device__ __forceinline__ u32 f2bf(float x) {
  union { float f; u32 u; } v; v.f = x;
  return (v.u + 0x7FFFu + ((v.u >> 16) & 1u)) >> 16;
}
__device__ __forceinline__ u32 pk2(float a, float b) { return f2bf(a) | (f2bf(b) << 16); }
// split f32 -> (hi bf16, lo bf16) packed low|high in one u32
__device__ __forceinline__ u32 split_pack(float x) {
  u32 h = f2bf(x);
  union { u32 u; float f; } hf; hf.u = h << 16;
  u32 l = f2bf(x - hf.f);
  return h | (l << 16);
}
// split two f32 into separate hi-pair / lo-pair u32 words
__device__ __forceinline__ void split2(float a, float b, u32& hw, u32& lw) {
  u32 ha = f2bf(a), hb = f2bf(b);
  union { u32 u; float f; } fa, fb; fa.u = ha << 16; fb.u = hb << 16;
  hw = ha | (hb << 16);
  lw = f2bf(a - fa.f) | (f2bf(b - fb.f) << 16);
}
// byte-perm helpers: build bf16x8 from 8 packed u32 (low plane / high plane)
__device__ __forceinline__ bf16x8 plane_lo(uint4 a, uint4 b) {
  union { u32 u[4]; bf16x8 v; } r;
  r.u[0] = __builtin_amdgcn_perm(a.y, a.x, 0x05040100u);
  r.u[1] = __builtin_amdgcn_perm(a.w, a.z, 0x05040100u);
  r.u[2] = __builtin_amdgcn_perm(b.y, b.x, 0x05040100u);
  r.u[3] = __builtin_amdgcn_perm(b.w, b.z, 0x05040100u);
  return r.v;
}
__device__ __forceinline__ bf16x8 plane_hi(uint4 a, uint4 b) {
  union { u32 u[4]; bf16x8 v; } r;
  r.u[0] = __builtin_amdgcn_perm(a.y, a.x, 0x07060302u);
  r.u[1] = __builtin_amdgcn_perm(a.w, a.z, 0x07060302u);
  r.u[2] = __builtin_amdgcn_perm(b.y, b.x, 0x07060302u);
  r.u[3] = __builtin_amdgcn_perm(b.w, b.z, 0x07060302u);
  return r.v;
}
#define ELU1(x) ((x) > 0.f ? (x) + 1.f : expf(x))
// XOR swizzle at 8-ushort granularity: row-major [64][64] bf16 tile
#define SWZ(row, kblk) ((row)*64 + (((kblk) ^ ((row)&7))*8))
#define SPLIT8(F0, F1, UH, UL, SCALE) do { \
  split2((F0).x*(SCALE), (F0).y*(SCALE), (UH).x, (UL).x); \
  split2((F0).z*(SCALE), (F0).w*(SCALE), (UH).y, (UL).y); \
  split2((F1).x*(SCALE), (F1).y*(SCALE), (UH).z, (UL).z); \
  split2((F1).z*(SCALE), (F1).w*(SCALE), (UH).w, (UL).w); } while(0)

// ---------------- Kernel P: fused prologue ----------------
__global__ __launch_bounds__(256) void prep_kernel(const float* __restrict__ q,
                                                   const float* __restrict__ k,
                                                   const float* __restrict__ v,
                                                   u16* __restrict__ kvt16,
                                                   float* __restrict__ ksum,
                                                   double* __restrict__ qrep,
                                                   double* __restrict__ krep) {
  __shared__ float smem[3*BS*D];          // 48 KB
  int bid = blockIdx.x;
  int tid = threadIdx.x;
  if (bid >= 256) {
    double* qred = (double*)smem;
    int r = bid - 256;                    // h*NB + bi
    int h = r >> 5, bi = r & 31;
    int d = tid & 63, quarter = tid >> 6;
    double s = 0.0;
    for (int t = quarter*16; t < quarter*16 + 16; ++t)
      s += (double)q[((bi*BS + t)*H + h)*D + d];
    qred[quarter*64 + d] = s;
    __syncthreads();
    if (tid < 64)
      qrep[r*D + tid] = (qred[tid] + qred[64+tid] + qred[128+tid] + qred[192+tid]) * (1.0/64.0);
    return;
  }
  float* kf   = smem;                     // [s][d] elu(k)+1
  float* vv   = smem + BS*D;              // [s][c]
  float* kraw = smem + 2*BS*D;            // [s][d] raw k
  int h = bid >> 5, ki = bid & 31;
  int sr = tid >> 2, cgp = tid & 3;
  const float4* kb = (const float4*)(k + ((ki*BS + sr)*H + h)*D);
  const float4* vb = (const float4*)(v + ((ki*BS + sr)*H + h)*D);
#pragma unroll
  for (int m = 0; m < 4; ++m) {
    float4 kk = kb[cgp*4 + m];
    float4 vx = vb[cgp*4 + m];
    int c = cgp*16 + m*4;
    *(float4*)&kraw[sr*D + c] = kk;
    kf[sr*D + c + 0] = ELU1(kk.x);
    kf[sr*D + c + 1] = ELU1(kk.y);
    kf[sr*D + c + 2] = ELU1(kk.z);
    kf[sr*D + c + 3] = ELU1(kk.w);
    *(float4*)&vv[sr*D + c] = vx;
  }
  __syncthreads();
  int c = tid & 63, dg = tid >> 6, d0 = dg*16;
  float acc[16];
#pragma unroll
  for (int j = 0; j < 16; ++j) acc[j] = 0.f;
#pragma unroll 4
  for (int s2 = 0; s2 < BS; ++s2) {
    float vval = vv[s2*D + c];
    const float4* kr = (const float4*)&kf[s2*D + d0];
    float4 a0 = kr[0], a1 = kr[1], a2 = kr[2], a3 = kr[3];
    acc[0]  += vval*a0.x; acc[1]  += vval*a0.y; acc[2]  += vval*a0.z; acc[3]  += vval*a0.w;
    acc[4]  += vval*a1.x; acc[5]  += vval*a1.y; acc[6]  += vval*a1.z; acc[7]  += vval*a1.w;
    acc[8]  += vval*a2.x; acc[9]  += vval*a2.y; acc[10] += vval*a2.z; acc[11] += vval*a2.w;
    acc[12] += vval*a3.x; acc[13] += vval*a3.y; acc[14] += vval*a3.z; acc[15] += vval*a3.w;
  }
  u16* op = kvt16 + (size_t)bid*4096 + c*64 + d0;
  uint4 P0, P1;
  P0.x = pk2(acc[0],acc[1]);   P0.y = pk2(acc[2],acc[3]);
  P0.z = pk2(acc[4],acc[5]);   P0.w = pk2(acc[6],acc[7]);
  P1.x = pk2(acc[8],acc[9]);   P1.y = pk2(acc[10],acc[11]);
  P1.z = pk2(acc[12],acc[13]); P1.w = pk2(acc[14],acc[15]);
  *(uint4*)(op + 0) = P0;
  *(uint4*)(op + 8) = P1;
  if (dg == 0) {
    float ks = 0.f;
    for (int s2 = 0; s2 < BS; ++s2) ks += kf[s2*D + c];
    ksum[bid*D + c] = ks;
    double m = 0.0;
    for (int s2 = 0; s2 < BS; ++s2) m += (double)kraw[s2*D + c];
    krep[bid*D + c] = m * (1.0/64.0);
  }
}

// ---------------- Kernel B: bscores + per-row stats (32 blocks) ----------------
__global__ __launch_bounds__(256) void bscore_stats_kernel(const double* __restrict__ qrep,
                                                           const double* __restrict__ krep,
                                                           double* __restrict__ rowmin,
                                                           double* __restrict__ rowmax,
                                                           double* __restrict__ rowvar) {
  __shared__ double qs[8*64];
  __shared__ double ks[32*65];
  int b = blockIdx.x;
  int h = b >> 2;
  int r0 = b*8;
  int tid = threadIdx.x;
  for (int i = tid; i < 512; i += 256) qs[i] = qrep[(size_t)r0*64 + i];
  for (int i = tid; i < 2048; i += 256) ks[(i >> 6)*65 + (i & 63)] = krep[(size_t)h*2048 + i];
  __syncthreads();
  int lr = tid >> 5, ki = tid & 31;
  double s = 0.0;
  const double* qr = qs + lr*64;
  const double* kr = ks + ki*65;
#pragma unroll 16
  for (int d = 0; d < D; ++d) s += qr[d]*kr[d];
  double bs = s * 0.125;
  double rmax = bs, rmin = bs;
#pragma unroll
  for (int m = 1; m < 32; m <<= 1) {
    rmax = fmax(rmax, __shfl_xor(rmax, m, 64));
    rmin = fmin(rmin, __shfl_xor(rmin, m, 64));
  }
  double e = exp(bs - rmax);
  double S = e, S2 = e*e;
#pragma unroll
  for (int m = 1; m < 32; m <<= 1) {
    S  += __shfl_xor(S,  m, 64);
    S2 += __shfl_xor(S2, m, 64);
  }
  if (ki == 0) {
    double invS = 1.0 / S;
    double sp = S * invS;
    double mu = sp * (1.0/32.0);
    double var = (S2*invS*invS - 2.0*mu*sp + 32.0*mu*mu) * (1.0/31.0);
    rowmin[r0 + lr] = rmin;
    rowmax[r0 + lr] = rmax;
    rowvar[r0 + lr] = var;
  }
}

// ---------------- Kernel F: per-row flags (1 block) ----------------
__global__ __launch_bounds__(256) void flags_kernel(const double* __restrict__ rowmin,
                                                    const double* __restrict__ rowmax,
                                                    const double* __restrict__ rowvar,
                                                    int* __restrict__ flags) {
  __shared__ double redA[4];
  __shared__ double redB[4];
  int tid = threadIdx.x;
  int lane = tid & 63, wid = tid >> 6;
  double x = rowmin[tid];
#pragma unroll
  for (int m = 1; m < 64; m <<= 1) x = fmin(x, __shfl_xor(x, m, 64));
  if (lane == 0) redA[wid] = x;
  __syncthreads();
  double gmin = fmin(fmin(redA[0], redA[1]), fmin(redA[2], redA[3]));
  double rng = rowmax[tid] - gmin;
  if (rng < 1e-6) rng = 1e-6;
  double imp = rowvar[tid] * rng;
  __syncthreads();
  double a = imp, b2 = imp;
#pragma unroll
  for (int m = 1; m < 64; m <<= 1) {
    a  = fmin(a,  __shfl_xor(a,  m, 64));
    b2 = fmax(b2, __shfl_xor(b2, m, 64));
  }
  if (lane == 0) { redA[wid] = a; redB[wid] = b2; }
  __syncthreads();
  double imin = fmin(fmin(redA[0], redA[1]), fmin(redA[2], redA[3]));
  double imax = fmax(fmax(redB[0], redB[1]), fmax(redB[2], redB[3]));
  double impn = (imp - imin) / (imax - imin + 1e-6);
  flags[tid] = (impn >= 0.5) ? 2 : ((impn <= 0.01) ? 0 : 1);
}

// ---------------- Kernel D: main — ki-split, critical path in split-bf16 MFMA ----------------
__global__ __launch_bounds__(256) void main_kernel(
    const float* __restrict__ q, const float* __restrict__ k, const float* __restrict__ v,
    const u16* __restrict__ kvt16, const float* __restrict__ ksum,
    const int* __restrict__ flags, float* __restrict__ pacc, float* __restrict__ pw) {
  __shared__ __align__(16) float smem[16384];   // 64 KB -> 2 blocks/CU
  int bid = blockIdx.x;
  int rowid = bid >> 2;                   // h*NB + qi   (KSPLIT=4)
  int split = bid & (KSPLIT - 1);
  int h = rowid >> 5, qi = rowid & 31;
  int k0 = split * KCH;
  int tid = threadIdx.x;
  int row = tid >> 2, cgp = tid & 3, c0 = cgp*16;
  int lane = tid & 63;
  int w = tid >> 6, m = lane & 15, q4 = lane >> 4;

  float* paccp = pacc + (size_t)bid * 4096;
  float* pwp   = pw   + (size_t)bid * 64;

  int flag = flags[rowid];
  if (flag == 0) {
    if (tid < 64) pwp[tid] = 0.f;
    return;
  }

  if (flag == 1) {
    // ---- marginal: linear (ELU+1) attention via bf16 MFMA, double-buffered ----
    u16*  qfb  = (u16*)smem;              // [64][64] bf16, swizzled          (8 KB)
    u16*  kvb  = (u16*)(smem + 2048);     // 2 x [64][64] bf16, swizzled      (16 KB)
    float* idens = smem + 6144;           // [64][KCH] 1/den                  (2 KB)
    float* wsl   = smem + 6656;           // [64]
    float* kslc  = smem + 6720;           // [KCH][64] k_sum slice            (2 KB)

    {
      const float4* kss = (const float4*)(ksum + (size_t)(h*NB + k0)*D);
      for (int i = tid; i < KCH*16; i += 256) ((float4*)kslc)[i] = kss[i];
    }
    float qf[16];
    {
      const float4* qp = (const float4*)(q + ((qi*BS + row)*H + h)*D + c0);
      float4 q0 = qp[0], q1 = qp[1], q2 = qp[2], q3 = qp[3];
      qf[0]=ELU1(q0.x); qf[1]=ELU1(q0.y); qf[2]=ELU1(q0.z); qf[3]=ELU1(q0.w);
      qf[4]=ELU1(q1.x); qf[5]=ELU1(q1.y); qf[6]=ELU1(q1.z); qf[7]=ELU1(q1.w);
      qf[8]=ELU1(q2.x); qf[9]=ELU1(q2.y); qf[10]=ELU1(q2.z); qf[11]=ELU1(q2.w);
      qf[12]=ELU1(q3.x); qf[13]=ELU1(q3.y); qf[14]=ELU1(q3.z); qf[15]=ELU1(q3.w);
      uint4 p0, p1;
      p0.x = pk2(qf[0],qf[1]);  p0.y = pk2(qf[2],qf[3]);
      p0.z = pk2(qf[4],qf[5]);  p0.w = pk2(qf[6],qf[7]);
      p1.x = pk2(qf[8],qf[9]);  p1.y = pk2(qf[10],qf[11]);
      p1.z = pk2(qf[12],qf[13]); p1.w = pk2(qf[14],qf[15]);
      *(uint4*)&qfb[SWZ(row, cgp*2)]     = p0;
      *(uint4*)&qfb[SWZ(row, cgp*2 + 1)] = p1;
    }
    const u16* kvbase = kvt16 + (size_t)(h*NB + k0)*4096 + (size_t)row*64 + c0;
    uint4 u0 = *(const uint4*)(kvbase + 0);
    uint4 u1 = *(const uint4*)(kvbase + 8);
    __syncthreads();
    {
      float wloc = 0.f;
      for (int kk = 0; kk < KCH; ++kk) {
        float pd = 0.f;
#pragma unroll
        for (int j = 0; j < 16; ++j) pd += qf[j] * kslc[kk*64 + c0 + j];
        pd += __shfl_xor(pd, 1, 64);
        pd += __shfl_xor(pd, 2, 64);
        float den = pd + FEPS;
        if (cgp == 0) idens[row*KCH + kk] = 1.0f / den;
        wloc += den;
      }
      if (cgp == 0) wsl[row] = wloc;
    }
    *(uint4*)&kvb[SWZ(row, cgp*2)]     = u0;
    *(uint4*)&kvb[SWZ(row, cgp*2 + 1)] = u1;

    bf16x8 aLo = *(const bf16x8*)&qfb[SWZ(w*16 + m, q4)];
    bf16x8 aHi = *(const bf16x8*)&qfb[SWZ(w*16 + m, 4 + q4)];
    int rbase = w*16 + q4*4;
    float acc[16];
#pragma unroll
    for (int j = 0; j < 16; ++j) acc[j] = 0.f;

    for (int kk = 0; kk < KCH; ++kk) {
      if (kk + 1 < KCH) {
        const u16* kvp = kvbase + (size_t)(kk+1)*4096;
        u0 = *(const uint4*)(kvp + 0);
        u1 = *(const uint4*)(kvp + 8);
      }
      __syncthreads();
      const u16* kb = kvb + (kk & 1)*4096;
      float i0 = idens[(rbase + 0)*KCH + kk];
      float i1 = idens[(rbase + 1)*KCH + kk];
      float i2 = idens[(rbase + 2)*KCH + kk];
      float i3 = idens[(rbase + 3)*KCH + kk];
      floatx4 zz = {0.f, 0.f, 0.f, 0.f};
#pragma unroll
      for (int t = 0; t < 4; ++t) {
        bf16x8 bLo = *(const bf16x8*)&kb[SWZ(t*16 + m, q4)];
        bf16x8 bHi = *(const bf16x8*)&kb[SWZ(t*16 + m, 4 + q4)];
        floatx4 c4 = __builtin_amdgcn_mfma_f32_16x16x32_bf16(aLo, bLo, zz, 0, 0, 0);
        c4 = __builtin_amdgcn_mfma_f32_16x16x32_bf16(aHi, bHi, c4, 0, 0, 0);
        acc[t*4+0] += c4[0]*i0;
        acc[t*4+1] += c4[1]*i1;
        acc[t*4+2] += c4[2]*i2;
        acc[t*4+3] += c4[3]*i3;
      }
      if (kk + 1 < KCH) {
        u16* kw = kvb + ((kk+1) & 1)*4096;
        *(uint4*)&kw[SWZ(row, cgp*2)]     = u0;
        *(uint4*)&kw[SWZ(row, cgp*2 + 1)] = u1;
      }
    }
#pragma unroll
    for (int r = 0; r < 4; ++r)
#pragma unroll
      for (int t = 0; t < 4; ++t)
        paccp[(rbase + r)*64 + t*16 + m] = acc[t*4 + r];
    if (tid < 64) pwp[tid] = wsl[tid];
    return;
  }

  // ---- critical: split-bf16 (3-term) MFMA softmax attention over KCH k-blocks ----
  // S = Qh Kh + Qh Kl + Ql Kh ; O += (Ph Vh + Ph Vl + Pl Vh) * inv_rowsum
  u16* qhi = (u16*)smem;                  // [64][64] bf16 swz (8 KB)
  u16* qlo = (u16*)(smem + 2048);         // 8 KB
  u16* khi = (u16*)(smem + 4096);         // 8 KB
  u16* klo = (u16*)(smem + 6144);         // 8 KB
  u32* vt32 = (u32*)(smem + 8192);        // V^T [d][j] packed hi|lo<<16, swz (16 KB)
  u32* p32  = (u32*)(smem + 12288);       // P   [i][j] packed hi|lo<<16, swz (16 KB)

  // stage Q (scaled 1/8, split hi/lo) once
  {
    const float4* qp = (const float4*)(q + ((qi*BS + row)*H + h)*D + c0);
    float4 q0 = qp[0], q1 = qp[1], q2 = qp[2], q3 = qp[3];
    uint4 UH, UL;
    SPLIT8(q0, q1, UH, UL, 0.125f);
    *(uint4*)&qhi[SWZ(row, cgp*2)] = UH;
    *(uint4*)&qlo[SWZ(row, cgp*2)] = UL;
    SPLIT8(q2, q3, UH, UL, 0.125f);
    *(uint4*)&qhi[SWZ(row, cgp*2 + 1)] = UH;
    *(uint4*)&qlo[SWZ(row, cgp*2 + 1)] = UL;
  }
  // prefetch first K/V tile into registers
  float4 kreg[4], vreg[4];
  {
    const float4* kp = (const float4*)(k + ((k0*BS + row)*H + h)*D + c0);
    const float4* vp = (const float4*)(v + ((k0*BS + row)*H + h)*D + c0);
#pragma unroll
    for (int mm = 0; mm < 4; ++mm) { kreg[mm] = kp[mm]; vreg[mm] = vp[mm]; }
  }
  __syncthreads();                        // Q tiles visible
  // persistent Q A-frags (lane m = row within wave tile, q4 = k-chunk)
  bf16x8 qh0 = *(const bf16x8*)&qhi[SWZ(w*16 + m, q4)];
  bf16x8 qh1 = *(const bf16x8*)&qhi[SWZ(w*16 + m, 4 + q4)];
  bf16x8 ql0 = *(const bf16x8*)&qlo[SWZ(w*16 + m, q4)];
  bf16x8 ql1 = *(const bf16x8*)&qlo[SWZ(w*16 + m, 4 + q4)];

  int rbase = w*16 + q4*4;
  int ibase = (w*16 + m)*64;
  float acc[16];
#pragma unroll
  for (int j = 0; j < 16; ++j) acc[j] = 0.f;
  float wsum4[4] = {0.f, 0.f, 0.f, 0.f};

#pragma unroll 1
  for (int kk = 0; kk < KCH; ++kk) {
    // ---- stage K (split planes) and V^T (packed) from regs ----
    {
      uint4 UH, UL;
      SPLIT8(kreg[0], kreg[1], UH, UL, 1.0f);
      *(uint4*)&khi[SWZ(row, cgp*2)] = UH;
      *(uint4*)&klo[SWZ(row, cgp*2)] = UL;
      SPLIT8(kreg[2], kreg[3], UH, UL, 1.0f);
      *(uint4*)&khi[SWZ(row, cgp*2 + 1)] = UH;
      *(uint4*)&klo[SWZ(row, cgp*2 + 1)] = UL;
#pragma unroll
      for (int mm = 0; mm < 4; ++mm) {
        float4 vx = vreg[mm];
        int dd = c0 + mm*4;
        vt32[(dd+0)*64 + ((((row>>3)) ^ ((dd+0)&7))*8) + (row&7)] = split_pack(vx.x);
        vt32[(dd+1)*64 + ((((row>>3)) ^ ((dd+1)&7))*8) + (row&7)] = split_pack(vx.y);
        vt32[(dd+2)*64 + ((((row>>3)) ^ ((dd+2)&7))*8) + (row&7)] = split_pack(vx.z);
        vt32[(dd+3)*64 + ((((row>>3)) ^ ((dd+3)&7))*8) + (row&7)] = split_pack(vx.w);
      }
    }
    __syncthreads();                      // staged tiles visible
    if (kk + 1 < KCH) {
      int ki1 = k0 + kk + 1;
      const float4* kp = (const float4*)(k + ((ki1*BS + row)*H + h)*D + c0);
      const float4* vp = (const float4*)(v + ((ki1*BS + row)*H + h)*D + c0);
#pragma unroll
      for (int mm = 0; mm < 4; ++mm) { kreg[mm] = kp[mm]; vreg[mm] = vp[mm]; }
    }
    // ---- scores: 16x16x32 MFMA, 3-term split, K-dim d=64 (2 steps) ----
    float sc[16];
#pragma unroll
    for (int t = 0; t < 4; ++t) {
      bf16x8 bh0 = *(const bf16x8*)&khi[SWZ(t*16 + m, q4)];
      bf16x8 bh1 = *(const bf16x8*)&khi[SWZ(t*16 + m, 4 + q4)];
      bf16x8 bl0 = *(const bf16x8*)&klo[SWZ(t*16 + m, q4)];
      bf16x8 bl1 = *(const bf16x8*)&klo[SWZ(t*16 + m, 4 + q4)];
      floatx4 c4 = {0.f, 0.f, 0.f, 0.f};
      c4 = __builtin_amdgcn_mfma_f32_16x16x32_bf16(qh0, bh0, c4, 0, 0, 0);
      c4 = __builtin_amdgcn_mfma_f32_16x16x32_bf16(qh1, bh1, c4, 0, 0, 0);
      c4 = __builtin_amdgcn_mfma_f32_16x16x32_bf16(qh0, bl0, c4, 0, 0, 0);
      c4 = __builtin_amdgcn_mfma_f32_16x16x32_bf16(qh1, bl1, c4, 0, 0, 0);
      c4 = __builtin_amdgcn_mfma_f32_16x16x32_bf16(ql0, bh0, c4, 0, 0, 0);
      c4 = __builtin_amdgcn_mfma_f32_16x16x32_bf16(ql1, bh1, c4, 0, 0, 0);
      sc[t*4+0] = c4[0]; sc[t*4+1] = c4[1]; sc[t*4+2] = c4[2]; sc[t*4+3] = c4[3];
    }
    // ---- softmax per q-row (row = rbase+r spread over 16 m-lanes x 4 t-regs) ----
    float inv4[4];
#pragma unroll
    for (int r = 0; r < 4; ++r) {
      float mxr = fmaxf(fmaxf(sc[r], sc[4+r]), fmaxf(sc[8+r], sc[12+r]));
      mxr = fmaxf(mxr, __shfl_xor(mxr, 1, 64));
      mxr = fmaxf(mxr, __shfl_xor(mxr, 2, 64));
      mxr = fmaxf(mxr, __shfl_xor(mxr, 4, 64));
      mxr = fmaxf(mxr, __shfl_xor(mxr, 8, 64));
      float e0 = expf(sc[r] - mxr),  e1 = expf(sc[4+r] - mxr);
      float e2 = expf(sc[8+r] - mxr), e3 = expf(sc[12+r] - mxr);
      sc[r] = e0; sc[4+r] = e1; sc[8+r] = e2; sc[12+r] = e3;
      float es = e0 + e1 + e2 + e3;
      es += __shfl_xor(es, 1, 64);
      es += __shfl_xor(es, 2, 64);
      es += __shfl_xor(es, 4, 64);
      es += __shfl_xor(es, 8, 64);
      float iv = 1.0f / es;
      wsum4[r] += es * iv;
      inv4[r] = iv;
    }
    // ---- P split-pack to wave-private LDS plane (C-layout -> A-layout bounce) ----
#pragma unroll
    for (int t = 0; t < 4; ++t) {
#pragma unroll
      for (int r = 0; r < 4; ++r) {
        int i2 = rbase + r;
        int jg = t*2 + (m >> 3);
        p32[i2*64 + ((jg ^ (i2 & 7))*8) + (m & 7)] = split_pack(sc[t*4+r]);
      }
    }
    asm volatile("s_waitcnt lgkmcnt(0)" ::: "memory");
    // ---- PV: A = P (rows i), B = V^T (rows d); 3-term split ----
    uint4 a00 = *(const uint4*)&p32[ibase + ((q4 ^ (m & 7))*8)];
    uint4 a01 = *(const uint4*)&p32[ibase + ((q4 ^ (m & 7))*8) + 4];
    uint4 a10 = *(const uint4*)&p32[ibase + (((4 + q4) ^ (m & 7))*8)];
    uint4 a11 = *(const uint4*)&p32[ibase + (((4 + q4) ^ (m & 7))*8) + 4];
    bf16x8 aPh0 = plane_lo(a00, a01), aPl0 = plane_hi(a00, a01);
    bf16x8 aPh1 = plane_lo(a10, a11), aPl1 = plane_hi(a10, a11);
#pragma unroll
    for (int t = 0; t < 4; ++t) {
      int dm = t*16 + m;
      int vb0 = dm*64 + ((q4 ^ (m & 7))*8);
      int vb1 = dm*64 + (((4 + q4) ^ (m & 7))*8);
      uint4 v00 = *(const uint4*)&vt32[vb0];
      uint4 v01 = *(const uint4*)&vt32[vb0 + 4];
      uint4 v10 = *(const uint4*)&vt32[vb1];
      uint4 v11 = *(const uint4*)&vt32[vb1 + 4];
      bf16x8 vh0 = plane_lo(v00, v01), vl0 = plane_hi(v00, v01);
      bf16x8 vh1 = plane_lo(v10, v11), vl1 = plane_hi(v10, v11);
      floatx4 c4 = {0.f, 0.f, 0.f, 0.f};
      c4 = __builtin_amdgcn_mfma_f32_16x16x32_bf16(aPh0, vh0, c4, 0, 0, 0);
      c4 = __builtin_amdgcn_mfma_f32_16x16x32_bf16(aPh1, vh1, c4, 0, 0, 0);
      c4 = __builtin_amdgcn_mfma_f32_16x16x32_bf16(aPh0, vl0, c4, 0, 0, 0);
      c4 = __builtin_amdgcn_mfma_f32_16x16x32_bf16(aPh1, vl1, c4, 0, 0, 0);
      c4 = __builtin_amdgcn_mfma_f32_16x16x32_bf16(aPl0, vh0, c4, 0, 0, 0);
      c4 = __builtin_amdgcn_mfma_f32_16x16x32_bf16(aPl1, vh1, c4, 0, 0, 0);
      acc[t*4+0] += c4[0]*inv4[0];
      acc[t*4+1] += c4[1]*inv4[1];
      acc[t*4+2] += c4[2]*inv4[2];
      acc[t*4+3] += c4[3]*inv4[3];
    }
    __syncthreads();                      // all reads done before next staging
  }
  // ---- write f32 partials ----
#pragma unroll
  for (int r = 0; r < 4; ++r)
#pragma unroll
    for (int t = 0; t < 4; ++t)
      paccp[(rbase + r)*64 + t*16 + m] = acc[t*4 + r];
  if (m == 0) {
#pragma unroll
    for (int r = 0; r < 4; ++r) pwp[rbase + r] = wsum4[r];
  }
}

// ---------------- Kernel C: combine partials ----------------
__global__ __launch_bounds__(256) void combine_kernel(const float* __restrict__ pacc,
                                                      const float* __restrict__ pw,
                                                      float* __restrict__ out) {
  int rowid = blockIdx.x;                 // h*NB + qi
  int h = rowid >> 5, qi = rowid & 31;
  int tid = threadIdx.x;
  int row = tid >> 2, c0 = (tid & 3)*16;
  float w = 0.f;
  const float* pwb = pw + (size_t)rowid * KSPLIT * 64 + row;
#pragma unroll
  for (int s = 0; s < KSPLIT; ++s) w += pwb[s*64];
  float* op = out + ((qi*BS + row)*H + h)*D + c0;
  if (w == 0.f) {
    float4 z = make_float4(0.f, 0.f, 0.f, 0.f);
    ((float4*)op)[0] = z; ((float4*)op)[1] = z; ((float4*)op)[2] = z; ((float4*)op)[3] = z;
    return;
  }
  floatx4 s0 = {0,0,0,0}, s1 = {0,0,0,0}, s2 = {0,0,0,0}, s3 = {0,0,0,0};
  const float* base = pacc + (size_t)rowid * KSPLIT * 4096 + row*64 + c0;
#pragma unroll
  for (int s = 0; s < KSPLIT; ++s) {
    const floatx4* p4 = (const floatx4*)(base + (size_t)s*4096);
    s0 += p4[0]; s1 += p4[1]; s2 += p4[2]; s3 += p4[3];
  }
  float wd = 1.0f / (w + FEPS);
  ((float4*)op)[0] = make_float4(s0[0]*wd, s0[1]*wd, s0[2]*wd, s0[3]*wd);
  ((float4*)op)[1] = make_float4(s1[0]*wd, s1[1]*wd, s1[2]*wd, s1[3]*wd);
  ((float4*)op)[2] = make_float4(s2[0]*wd, s2[1]*wd, s2[2]*wd, s2[3]*wd);
  ((float4*)op)[3] = make_float4(s3[0]*wd, s3[1]*wd, s3[2]*wd, s3[3]*wd);
}

extern "C" void kernel_launch(void* const* d_in, const int* in_sizes, int n_in,
                              void* d_out, int out_size, void* d_ws, size_t ws_size,
                              hipStream_t stream) {
  const float* q = (const float*)d_in[0];
  const float* k = (const float*)d_in[1];
  const float* v = (const float*)d_in[2];
  float* out = (float*)d_out;
  char* ws = (char*)d_ws;
  u16*    kvw  = (u16*)   (ws + 0);                    // 2 MB
  float*  ksw  = (float*) (ws + 2097152);
  double* krep = (double*)(ws + 2162688);
  double* qrep = (double*)(ws + 2293760);
  double* rmn  = (double*)(ws + 2424832);
  double* rmx  = (double*)(ws + 2426880);
  double* rvr  = (double*)(ws + 2428928);
  int*    flg  = (int*)   (ws + 2430976);
  float*  pacc = (float*) (ws + 4194304);              // 1024*4096 f32 (16 MB)
  float*  pw   = (float*) (ws + 4194304 + 16777216);   // 1024*64 f32

  prep_kernel<<<512, 256, 0, stream>>>(q, k, v, kvw, ksw, qrep, krep);
  bscore_stats_kernel<<<32, 256, 0, stream>>>(qrep, krep, rmn, rmx, rvr);
  flags_kernel<<<1, 256, 0, stream>>>(rmn, rmx, rvr, flg);
  main_kernel<<<256*KSPLIT, 256, 0, stream>>>(q, k, v, kvw, ksw, flg, pacc, pw);
  combine_kernel<<<256, 256, 0, stream>>>(pacc, pw, out);
}